// Round 1
// baseline (161.143 us; speedup 1.0000x reference)
//
#include <hip/hip_runtime.h>

// MACD: EMA_slow(x) - EMA_fast(x) over time axis.
// x: [B, T=2048, F=8] fp32, contiguous, f fastest.
// Exact blocked scan: block per b, thread per 8-step t-chunk (all 8 f).

#define T_LEN 2048
#define FDIM 8
#define CHUNK 8
#define NCHUNK (T_LEN / CHUNK)   // 256 == blockDim.x

__device__ __forceinline__ float pow8(float v) {
    float v2 = v * v;
    float v4 = v2 * v2;
    return v4 * v4;
}

__global__ void macd_kernel(const float* __restrict__ x,
                            float* __restrict__ out) {
    const float AS  = (float)(2.0 / 27.0);   // alpha slow (N=26)
    const float AF  = (float)(2.0 / 13.0);   // alpha fast (N=12)
    const float OMS = 1.0f - AS;
    const float OMF = 1.0f - AF;

    const int b = blockIdx.x;
    const int c = threadIdx.x;               // chunk index 0..255

    const float* xb = x   + (size_t)b * (T_LEN * FDIM);
    float*       ob = out + (size_t)b * (T_LEN * FDIM);

    // ---------------- Phase 1: local zero-init EMAs, keep diffs in regs ----
    float ps[FDIM], pf[FDIM];
    float diff[CHUNK][FDIM];
#pragma unroll
    for (int f = 0; f < FDIM; ++f) { ps[f] = 0.f; pf[f] = 0.f; }

    const float4* xv = reinterpret_cast<const float4*>(xb + c * CHUNK * FDIM);
#pragma unroll
    for (int i = 0; i < CHUNK; ++i) {
        float4 lo = xv[i * 2 + 0];
        float4 hi = xv[i * 2 + 1];
        float xx[FDIM] = {lo.x, lo.y, lo.z, lo.w, hi.x, hi.y, hi.z, hi.w};
#pragma unroll
        for (int f = 0; f < FDIM; ++f) {
            ps[f] = AS * xx[f] + OMS * ps[f];
            pf[f] = AF * xx[f] + OMF * pf[f];
            diff[i][f] = ps[f] - pf[f];
        }
    }

    // ---------------- chunk-end values -> LDS (stride 17: conflict-free) ---
    __shared__ float carry[NCHUNK][2 * FDIM + 1];
#pragma unroll
    for (int f = 0; f < FDIM; ++f) {
        carry[c][2 * f + 0] = ps[f];
        carry[c][2 * f + 1] = pf[f];
    }
    __syncthreads();

    // ---------------- serial affine scan over 256 chunks (16 threads) ------
    // carry-in for chunk 0 is x[b][0][f] for both EMAs: y0 = a*x0+(1-a)*x0 = x0.
    if (threadIdx.x < 16) {
        const int f = threadIdx.x >> 1;
        const int w = threadIdx.x & 1;
        const float D = w ? pow8(OMF) : pow8(OMS);
        float Y = xb[f];
        for (int cc = 0; cc < NCHUNK; ++cc) {
            float pend = carry[cc][2 * f + w];
            carry[cc][2 * f + w] = Y;        // overwrite with carry-IN
            Y = pend + D * Y;
        }
    }
    __syncthreads();

    // ---------------- Phase 2: add geometric corrections, write out --------
    float ws[FDIM], wf[FDIM];
#pragma unroll
    for (int f = 0; f < FDIM; ++f) {
        ws[f] = OMS * carry[c][2 * f + 0];   // om_s^1 * Cs
        wf[f] = OMF * carry[c][2 * f + 1];   // om_f^1 * Cf
    }

    float4* ov = reinterpret_cast<float4*>(ob + c * CHUNK * FDIM);
#pragma unroll
    for (int i = 0; i < CHUNK; ++i) {
        float o[FDIM];
#pragma unroll
        for (int f = 0; f < FDIM; ++f) {
            o[f] = diff[i][f] + (ws[f] - wf[f]);
            ws[f] *= OMS;
            wf[f] *= OMF;
        }
        float4 lo = {o[0], o[1], o[2], o[3]};
        float4 hi = {o[4], o[5], o[6], o[7]};
        ov[i * 2 + 0] = lo;
        ov[i * 2 + 1] = hi;
    }
}

extern "C" void kernel_launch(void* const* d_in, const int* in_sizes, int n_in,
                              void* d_out, int out_size, void* d_ws, size_t ws_size,
                              hipStream_t stream) {
    (void)n_in; (void)d_ws; (void)ws_size; (void)out_size;
    const float* x = (const float*)d_in[0];
    float* out = (float*)d_out;
    const int B = in_sizes[0] / (T_LEN * FDIM);   // 4096
    macd_kernel<<<dim3(B), dim3(NCHUNK), 0, stream>>>(x, out);
}